// Round 1
// 10601.196 us; speedup vs baseline: 1.3105x; 1.3105x over previous
//
#include <hip/hip_runtime.h>
#include <hip/hip_bf16.h>
#include <cmath>

// Problem constants
#define BATCH 16
#define SEQ 256
#define EMBED 512
#define HIDDEN 1024
#define GATES 4096       // 4*HIDDEN
#define VOCAB 32000
#define MROWS 4096       // BATCH*SEQ
#define LOGITS_SZ 131072000  // 16*256*32000

typedef unsigned int u32;
typedef unsigned short u16;
typedef __attribute__((ext_vector_type(8))) short bf16x8;
typedef __attribute__((ext_vector_type(4))) float f32x4;

#define AS1 __attribute__((address_space(1)))
#define AS3 __attribute__((address_space(3)))

// ---------------- embedding gather ----------------
// X0[(s*16+b)*512 + e] = emb[x[b*256+s]*512 + e]
__global__ void embed_kernel(const int* __restrict__ x, const float* __restrict__ emb,
                             float* __restrict__ X0) {
    int r = blockIdx.x;            // r = s*16 + b
    int s = r >> 4, b = r & 15;
    int tok = x[b * SEQ + s];
    const float4* src = (const float4*)(emb + (size_t)tok * EMBED);
    float4* dst = (float4*)(X0 + (size_t)r * EMBED);
    for (int i = threadIdx.x; i < EMBED / 4; i += blockDim.x) dst[i] = src[i];
}

// ---------------- transpose W_hh [4096][1024] -> Wt [1024][4096] ----------------
__global__ void transpose_kernel(const float* __restrict__ W, float* __restrict__ Wt,
                                 int rows, int cols) {
    __shared__ float tile[32][33];
    int c0 = blockIdx.x * 32, r0 = blockIdx.y * 32;
    int tx = threadIdx.x & 31, ty = threadIdx.x >> 5;   // 256 threads: ty 0..7
    for (int i = ty; i < 32; i += 8)
        tile[i][tx] = W[(size_t)(r0 + i) * cols + (c0 + tx)];
    __syncthreads();
    for (int i = ty; i < 32; i += 8)
        Wt[(size_t)(c0 + i) * rows + (r0 + tx)] = tile[tx][i];
}

// ---------------- fp32 GEMM: C[M,N] = A[M,K] @ B[N,K]^T + b1 + b2 ----------------
// 128x128 block tile, BK=8, 256 threads, 8x8 microtile. (kept for layer projections)
__global__ __launch_bounds__(256) void gemm_bt(
    const float* __restrict__ A, const float* __restrict__ B,
    const float* __restrict__ b1, const float* __restrict__ b2,
    float* __restrict__ C, int M, int N, int K, int perm) {
    __shared__ float As[8][128];
    __shared__ float Bs[8][128];
    int tid = threadIdx.x;
    int bm = blockIdx.y, bn = blockIdx.x;
    int arow = tid >> 1;              // 0..127
    int ak4 = (tid & 1) * 4;          // 0 or 4
    const float* Ag = A + (size_t)(bm * 128 + arow) * K + ak4;
    const float* Bg = B + (size_t)(bn * 128 + arow) * K + ak4;
    int tx = tid & 15, ty = tid >> 4;

    float acc[8][8];
#pragma unroll
    for (int i = 0; i < 8; i++)
#pragma unroll
        for (int j = 0; j < 8; j++) acc[i][j] = 0.f;

    for (int k0 = 0; k0 < K; k0 += 8) {
        float4 a4 = *(const float4*)(Ag + k0);
        float4 b4 = *(const float4*)(Bg + k0);
        __syncthreads();
        As[ak4 + 0][arow] = a4.x; As[ak4 + 1][arow] = a4.y;
        As[ak4 + 2][arow] = a4.z; As[ak4 + 3][arow] = a4.w;
        Bs[ak4 + 0][arow] = b4.x; Bs[ak4 + 1][arow] = b4.y;
        Bs[ak4 + 2][arow] = b4.z; Bs[ak4 + 3][arow] = b4.w;
        __syncthreads();
#pragma unroll
        for (int k = 0; k < 8; k++) {
            float av[8], bv[8];
            *(float4*)(av + 0) = *(const float4*)&As[k][ty * 8 + 0];
            *(float4*)(av + 4) = *(const float4*)&As[k][ty * 8 + 4];
            *(float4*)(bv + 0) = *(const float4*)&Bs[k][tx * 8 + 0];
            *(float4*)(bv + 4) = *(const float4*)&Bs[k][tx * 8 + 4];
#pragma unroll
            for (int i = 0; i < 8; i++)
#pragma unroll
                for (int j = 0; j < 8; j++) acc[i][j] += av[i] * bv[j];
        }
    }

#pragma unroll
    for (int i = 0; i < 8; i++) {
        int r = bm * 128 + ty * 8 + i;
        int orow = perm ? ((r & 15) * SEQ + (r >> 4)) : r;
#pragma unroll
        for (int j = 0; j < 8; j += 4) {
            int c = bn * 128 + tx * 8 + j;
            float4 v;
            float bb0 = (b1 ? b1[c + 0] : 0.f) + (b2 ? b2[c + 0] : 0.f);
            float bb1 = (b1 ? b1[c + 1] : 0.f) + (b2 ? b2[c + 1] : 0.f);
            float bb2 = (b1 ? b1[c + 2] : 0.f) + (b2 ? b2[c + 2] : 0.f);
            float bb3 = (b1 ? b1[c + 3] : 0.f) + (b2 ? b2[c + 3] : 0.f);
            v.x = acc[i][j + 0] + bb0;
            v.y = acc[i][j + 1] + bb1;
            v.z = acc[i][j + 2] + bb2;
            v.w = acc[i][j + 3] + bb3;
            *(float4*)&C[(size_t)orow * N + c] = v;
        }
    }
}

// ---------------- fp32 -> bf16 conversion (RNE), 8 elems/thread ----------------
__device__ __forceinline__ u32 f2bf(float f) {
    u32 u = __float_as_uint(f);
    return (u + 0x7fffu + ((u >> 16) & 1u)) >> 16;
}

__global__ __launch_bounds__(256) void f32_to_bf16_kernel(
    const float* __restrict__ in, u16* __restrict__ out, int n8) {
    for (int i = blockIdx.x * 256 + threadIdx.x; i < n8; i += gridDim.x * 256) {
        float4 a = ((const float4*)in)[2 * (size_t)i + 0];
        float4 b = ((const float4*)in)[2 * (size_t)i + 1];
        uint4 o;
        o.x = f2bf(a.x) | (f2bf(a.y) << 16);
        o.y = f2bf(a.z) | (f2bf(a.w) << 16);
        o.z = f2bf(b.x) | (f2bf(b.y) << 16);
        o.w = f2bf(b.z) | (f2bf(b.w) << 16);
        ((uint4*)out)[i] = o;
    }
}

// ---------------- bf16 MFMA FC GEMM ----------------
// C[perm(r)][c] = sum_k Abf[r][k]*Bbf[c][k] + bias[c]
// 128x128 tile, BK=32, 4 waves (2x2), 4x4 16x16x32 frags per wave.
// global_load_lds width-16 staging (m97 structure).
__global__ __launch_bounds__(256) void fc_mfma(
    const u16* __restrict__ Abf,   // [MROWS][1024] bf16
    const u16* __restrict__ Bbf,   // [VOCAB][1024] bf16
    const float* __restrict__ bias,
    float* __restrict__ C) {
    const int K = HIDDEN;          // 1024
    const int N = VOCAB;
    __shared__ char smem[16384];   // As 8KB + Bs 8KB
    char* As = smem;
    char* Bs = smem + 8192;

    int tid = threadIdx.x;
    int w = tid >> 6, l = tid & 63;
    int bn = blockIdx.x, bm = blockIdx.y;
    int wr = w >> 1, wc = w & 1;
    int lr = l & 15, lk = l >> 4;

    f32x4 acc[4][4];
#pragma unroll
    for (int m = 0; m < 4; m++)
#pragma unroll
        for (int n = 0; n < 4; n++) acc[m][n] = {0.f, 0.f, 0.f, 0.f};

    // staging: thread tid loads 16B chunks. chunk q*256+tid -> row q*64+(tid>>2), k8=(tid&3)
    int srow = tid >> 2, skc = (tid & 3) * 8;
    const u16* ga0 = Abf + (size_t)(bm * 128 + srow) * K + skc;
    const u16* ga1 = Abf + (size_t)(bm * 128 + 64 + srow) * K + skc;
    const u16* gb0 = Bbf + (size_t)(bn * 128 + srow) * K + skc;
    const u16* gb1 = Bbf + (size_t)(bn * 128 + 64 + srow) * K + skc;
    // per-wave uniform LDS bases (HW adds lane*16)
    char* la0 = As + w * 1024;
    char* la1 = As + 4096 + w * 1024;
    char* lb0 = Bs + w * 1024;
    char* lb1 = Bs + 4096 + w * 1024;

    // per-lane fragment read offsets (row stride in LDS = 32 bf16 = 64B)
    int afo[4], bfo[4];
#pragma unroll
    for (int m = 0; m < 4; m++) afo[m] = (wr * 64 + m * 16 + lr) * 64 + lk * 16;
#pragma unroll
    for (int n = 0; n < 4; n++) bfo[n] = (wc * 64 + n * 16 + lr) * 64 + lk * 16;

    for (int k0 = 0; k0 < K; k0 += 32) {
        __syncthreads();   // all waves done reading previous tile
        __builtin_amdgcn_global_load_lds((const AS1 u32*)(const void*)(ga0 + k0),
                                         (AS3 u32*)(void*)la0, 16, 0, 0);
        __builtin_amdgcn_global_load_lds((const AS1 u32*)(const void*)(ga1 + k0),
                                         (AS3 u32*)(void*)la1, 16, 0, 0);
        __builtin_amdgcn_global_load_lds((const AS1 u32*)(const void*)(gb0 + k0),
                                         (AS3 u32*)(void*)lb0, 16, 0, 0);
        __builtin_amdgcn_global_load_lds((const AS1 u32*)(const void*)(gb1 + k0),
                                         (AS3 u32*)(void*)lb1, 16, 0, 0);
        __syncthreads();   // implicit vmcnt(0) drain -> tile resident

        bf16x8 af[4], bfr[4];
#pragma unroll
        for (int m = 0; m < 4; m++) af[m] = *(const bf16x8*)(As + afo[m]);
#pragma unroll
        for (int n = 0; n < 4; n++) bfr[n] = *(const bf16x8*)(Bs + bfo[n]);
#pragma unroll
        for (int m = 0; m < 4; m++)
#pragma unroll
            for (int n = 0; n < 4; n++)
                acc[m][n] = __builtin_amdgcn_mfma_f32_16x16x32_bf16(
                    af[m], bfr[n], acc[m][n], 0, 0, 0);
    }

    // epilogue: C/D layout col=lane&15, row=(lane>>4)*4+j  [m89-verified]
    int rbase = bm * 128 + wr * 64 + lk * 4;
    int cbase = bn * 128 + wc * 64 + lr;
#pragma unroll
    for (int m = 0; m < 4; m++) {
#pragma unroll
        for (int n = 0; n < 4; n++) {
            int c = cbase + n * 16;
            float bb = bias[c];
#pragma unroll
            for (int j = 0; j < 4; j++) {
                int r = rbase + m * 16 + j;
                int orow = (r & 15) * SEQ + (r >> 4);   // [B,S,V] layout
                C[(size_t)orow * N + c] = acc[m][n][j] + bb;
            }
        }
    }
}

// ---------------- per-step recurrent partial GEMM ----------------
// parts[kc][b][n] = sum_{k in chunk kc} ht[k][b] * Wt[k][n]
__global__ __launch_bounds__(256) void lstm_gemm(
    const float* __restrict__ Wt,   // [1024][4096]
    const float* __restrict__ ht,   // [1024][16]   (h transposed)
    float* __restrict__ parts) {    // [8][16][4096]
    int col = blockIdx.x * 128 + (threadIdx.x & 127);
    int bg = __builtin_amdgcn_readfirstlane(threadIdx.x >> 7);  // wave-uniform 0/1
    int b0 = bg * 8;
    int kc = blockIdx.y;            // 0..7, K-chunk of 128

    float acc[8];
#pragma unroll
    for (int i = 0; i < 8; i++) acc[i] = 0.f;

    const float* wp = Wt + (size_t)kc * 128 * GATES + col;
    const float* hp = ht + (size_t)kc * 128 * BATCH + b0;

#pragma unroll 4
    for (int k = 0; k < 128; k++) {
        float w = wp[(size_t)k * GATES];
        const float* h = hp + k * BATCH;   // wave-uniform address -> s_load
#pragma unroll
        for (int i = 0; i < 8; i++) acc[i] += h[i] * w;
    }

    float* outp = parts + ((size_t)kc * BATCH + b0) * GATES + col;
#pragma unroll
    for (int i = 0; i < 8; i++) outp[(size_t)i * GATES] = acc[i];
}

// ---------------- per-step LSTM elementwise update ----------------
__global__ __launch_bounds__(256) void lstm_update(
    const float* __restrict__ G,      // [4096][4096] rows (t*16+b)
    const float* __restrict__ parts,  // [8][16][4096]
    float* __restrict__ c_state,      // [16][1024] (this layer)
    float* __restrict__ Hseq,         // [4096][1024] rows (t*16+b)
    float* __restrict__ ht,           // [1024][16]
    int t) {
    int gid = blockIdx.x * 256 + threadIdx.x;
    int b = gid >> 10, j = gid & 1023;

    float g4[4];
#pragma unroll
    for (int gi = 0; gi < 4; gi++) {
        int n = gi * HIDDEN + j;
        float s = G[((size_t)(t * BATCH + b)) * GATES + n];
#pragma unroll
        for (int kc = 0; kc < 8; kc++)
            s += parts[((size_t)kc * BATCH + b) * GATES + n];
        g4[gi] = s;
    }
    float ig = 1.f / (1.f + __expf(-g4[0]));
    float fg = 1.f / (1.f + __expf(-g4[1]));
    float gg = tanhf(g4[2]);
    float og = 1.f / (1.f + __expf(-g4[3]));
    float c = fg * c_state[gid] + ig * gg;
    c_state[gid] = c;
    float h = og * tanhf(c);
    Hseq[((size_t)(t * BATCH + b)) * HIDDEN + j] = h;
    ht[j * BATCH + b] = h;
}

// ---------------- init & tails ----------------
__global__ void init_state(const float* __restrict__ h0, const float* __restrict__ c0,
                           float* __restrict__ c_ws, float* __restrict__ ht0,
                           float* __restrict__ ht1) {
    int gid = blockIdx.x * 256 + threadIdx.x;  // 32768
    c_ws[gid] = c0[gid];
    int l = gid >> 14, b = (gid >> 10) & 15, j = gid & 1023;
    float h = h0[gid];
    float* htp = l ? ht1 : ht0;
    htp[j * BATCH + b] = h;
}

__global__ void write_tails(const float* __restrict__ Hseq0, const float* __restrict__ Hseq1,
                            const float* __restrict__ c_ws, float* __restrict__ out) {
    int gid = blockIdx.x * 256 + threadIdx.x;  // 32768
    int l = gid >> 14, b = (gid >> 10) & 15, j = gid & 1023;
    const float* H = l ? Hseq1 : Hseq0;
    out[LOGITS_SZ + gid] = H[(size_t)((SEQ - 1) * BATCH + b) * HIDDEN + j];
    out[LOGITS_SZ + 32768 + gid] = c_ws[gid];
}

// ---------------- launch ----------------
extern "C" void kernel_launch(void* const* d_in, const int* in_sizes, int n_in,
                              void* d_out, int out_size, void* d_ws, size_t ws_size,
                              hipStream_t stream) {
    const int* x = (const int*)d_in[0];
    const float* h0 = (const float*)d_in[1];
    const float* c0 = (const float*)d_in[2];
    const float* emb = (const float*)d_in[3];
    const float* W_ih0 = (const float*)d_in[4];
    const float* W_hh0 = (const float*)d_in[5];
    const float* b_ih0 = (const float*)d_in[6];
    const float* b_hh0 = (const float*)d_in[7];
    const float* W_ih1 = (const float*)d_in[8];
    const float* W_hh1 = (const float*)d_in[9];
    const float* b_ih1 = (const float*)d_in[10];
    const float* b_hh1 = (const float*)d_in[11];
    const float* fc_W = (const float*)d_in[12];
    const float* fc_b = (const float*)d_in[13];
    float* out = (float*)d_out;
    float* ws = (float*)d_ws;

    // workspace layout (float offsets)
    const size_t OFF_WT0 = 0;                                  // 4096*1024
    const size_t OFF_WT1 = OFF_WT0 + (size_t)GATES * HIDDEN;   // 4096*1024
    const size_t OFF_X0 = OFF_WT1 + (size_t)GATES * HIDDEN;    // 4096*512  (reused: Hseq1 bf16)
    const size_t OFF_G = OFF_X0 + (size_t)MROWS * EMBED;       // 4096*4096 (reused: fc_W bf16)
    const size_t OFF_H0S = OFF_G + (size_t)MROWS * GATES;      // 4096*1024
    const size_t OFF_H1S = OFF_H0S + (size_t)MROWS * HIDDEN;   // 4096*1024
    const size_t OFF_PARTS = OFF_H1S + (size_t)MROWS * HIDDEN; // 8*16*4096
    const size_t OFF_C = OFF_PARTS + (size_t)8 * BATCH * GATES;    // 2*16*1024
    const size_t OFF_HT0 = OFF_C + 2 * BATCH * HIDDEN;             // 1024*16
    const size_t OFF_HT1 = OFF_HT0 + (size_t)HIDDEN * BATCH;       // 1024*16

    init_state<<<128, 256, 0, stream>>>(h0, c0, ws + OFF_C, ws + OFF_HT0, ws + OFF_HT1);
    embed_kernel<<<MROWS, 128, 0, stream>>>(x, emb, ws + OFF_X0);
    transpose_kernel<<<dim3(HIDDEN / 32, GATES / 32), 256, 0, stream>>>(W_hh0, ws + OFF_WT0, GATES, HIDDEN);
    transpose_kernel<<<dim3(HIDDEN / 32, GATES / 32), 256, 0, stream>>>(W_hh1, ws + OFF_WT1, GATES, HIDDEN);

    // layer 0: input projection for all timesteps
    gemm_bt<<<dim3(GATES / 128, MROWS / 128), 256, 0, stream>>>(
        ws + OFF_X0, W_ih0, b_ih0, b_hh0, ws + OFF_G, MROWS, GATES, EMBED, 0);
    for (int t = 0; t < SEQ; t++) {
        lstm_gemm<<<dim3(32, 8), 256, 0, stream>>>(ws + OFF_WT0, ws + OFF_HT0, ws + OFF_PARTS);
        lstm_update<<<64, 256, 0, stream>>>(ws + OFF_G, ws + OFF_PARTS,
                                            ws + OFF_C, ws + OFF_H0S, ws + OFF_HT0, t);
    }

    // layer 1
    gemm_bt<<<dim3(GATES / 128, MROWS / 128), 256, 0, stream>>>(
        ws + OFF_H0S, W_ih1, b_ih1, b_hh1, ws + OFF_G, MROWS, GATES, HIDDEN, 0);
    for (int t = 0; t < SEQ; t++) {
        lstm_gemm<<<dim3(32, 8), 256, 0, stream>>>(ws + OFF_WT1, ws + OFF_HT1, ws + OFF_PARTS);
        lstm_update<<<64, 256, 0, stream>>>(ws + OFF_G, ws + OFF_PARTS,
                                            ws + OFF_C + BATCH * HIDDEN, ws + OFF_H1S,
                                            ws + OFF_HT1, t);
    }

    // FC via bf16 MFMA: convert operands (G and X0 are dead now), then MFMA GEMM.
    // fc_W fp32 [32000][1024] -> bf16 in G space (needs 16.39M floats <= 16.78M)
    f32_to_bf16_kernel<<<4096, 256, 0, stream>>>(fc_W, (u16*)(ws + OFF_G), VOCAB * HIDDEN / 8);
    // Hseq1 fp32 [4096][1024] -> bf16 in X0 space (needs 2.097M floats == X0 size)
    f32_to_bf16_kernel<<<2048, 256, 0, stream>>>(ws + OFF_H1S, (u16*)(ws + OFF_X0),
                                                 MROWS * HIDDEN / 8);
    fc_mfma<<<dim3(VOCAB / 128, MROWS / 128), 256, 0, stream>>>(
        (const u16*)(ws + OFF_X0), (const u16*)(ws + OFF_G), fc_b, out);

    write_tails<<<128, 256, 0, stream>>>(ws + OFF_H0S, ws + OFF_H1S, ws + OFF_C, out);
}